// Round 4
// baseline (626.552 us; speedup 1.0000x reference)
//
#include <hip/hip_runtime.h>

typedef __attribute__((ext_vector_type(8))) short short8;
typedef __attribute__((ext_vector_type(4))) float f32x4;
typedef unsigned short u16;
typedef unsigned int u32;

#define MFMA16(a, b, c) __builtin_amdgcn_mfma_f32_16x16x32_bf16((a), (b), (c), 0, 0, 0)
#define SCALE 0.044194173824159216f /* 1/sqrt(512) */

__device__ __forceinline__ u16 f2bf(float f) {
    u32 u = __float_as_uint(f);
    u = (u + 0x7fffu + ((u >> 16) & 1u)) >> 16; // RNE
    return (u16)u;
}

// pack 8 f32 -> 8 bf16 (RNE) via v_cvt_pk_bf16_f32 (no builtin on gfx950)
__device__ __forceinline__ short8 pack8(f32x4 x, f32x4 y) {
    union { u32 w[4]; short8 s; } u;
    asm("v_cvt_pk_bf16_f32 %0, %1, %2" : "=v"(u.w[0]) : "v"(x[0]), "v"(x[1]));
    asm("v_cvt_pk_bf16_f32 %0, %1, %2" : "=v"(u.w[1]) : "v"(x[2]), "v"(x[3]));
    asm("v_cvt_pk_bf16_f32 %0, %1, %2" : "=v"(u.w[2]) : "v"(y[0]), "v"(y[1]));
    asm("v_cvt_pk_bf16_f32 %0, %1, %2" : "=v"(u.w[3]) : "v"(y[2]), "v"(y[3]));
    return u.s;
}

// XOR-swizzled LDS index for a [16][1024] f32 tile: spreads rows across bank
// groups so column-wise ds_read_b128 (phase 4) stays at the 2-lane/bank floor.
__device__ __forceinline__ int swz(int r, int c) {
    return (r << 10) + (c ^ ((r & 7) << 2));
}

struct CvtArgs {
    const float* s[7];
    u16* d[7];
};

// One launch converts q,k,v (y=0..2, 524288 float4) + Wq,Wk,Wv,Wo (y=3..6, 65536)
__global__ __launch_bounds__(256) void cvt_all(CvtArgs a) {
    int which = blockIdx.y;
    int n4 = (which < 3) ? 524288 : 65536;
    int i = blockIdx.x * 256 + threadIdx.x;
    if (i >= n4) return;
    // inputs are read exactly once -> non-temporal, don't pollute L2/L3
    f32x4 v = __builtin_nontemporal_load((const f32x4*)a.s[which] + i);
    unsigned long long p = (unsigned long long)f2bf(v[0])
                         | ((unsigned long long)f2bf(v[1]) << 16)
                         | ((unsigned long long)f2bf(v[2]) << 32)
                         | ((unsigned long long)f2bf(v[3]) << 48);
    ((unsigned long long*)a.d[which])[i] = p;
}

// rel[r,c] = sum_k pos_emb[r,k] * Wp[c,k] + bp[c], r<2047, c<64 -> bf16
__global__ __launch_bounds__(256) void rel_kernel(const float* __restrict__ pos_emb,
                                                  const float* __restrict__ Wp,
                                                  const float* __restrict__ bp,
                                                  u16* __restrict__ rel) {
    int idx = blockIdx.x * 256 + threadIdx.x;
    if (idx >= 2047 * 64) return;
    int r = idx >> 6, c = idx & 63;
    const float* pe = pos_emb + r * 64;
    const float* w  = Wp + c * 64;
    float acc = bp[c];
#pragma unroll
    for (int k = 0; k < 64; k++) acc += pe[k] * w[k];
    rel[r * 64 + c] = f2bf(acc);
}

// C[M,N] = A[M,K] @ B[N,K]^T, bf16 inputs, 64x64 block tile, 4 waves 2x2.
// MODE 0: q/k proj -> bf16 [B,H,S,dh], bias[n]
// MODE 1: v proj (A=Wv, B=value) -> bf16 vT [B,H,dh,S], bias[m]
// MODE 2: final   -> fp32 row-major, bias[n]
template <int MODE>
__global__ __launch_bounds__(256) void gemm_kernel(const u16* __restrict__ A,
                                                   const u16* __restrict__ B,
                                                   const float* __restrict__ bias,
                                                   void* __restrict__ Cout,
                                                   int M, int N, int K) {
    int tid = threadIdx.x;
    int w = tid >> 6, lane = tid & 63;
    int wi = w >> 1, wj = w & 1;
    int qd = lane >> 4, ln = lane & 15;
    int m_base = blockIdx.x * 64 + wi * 32;
    int n_base = blockIdx.y * 64 + wj * 32;
    f32x4 acc[2][2] = {};
    const u16* a0p = A + (long)(m_base + ln) * K + qd * 8;
    const u16* a1p = a0p + 16 * K;
    const u16* b0p = B + (long)(n_base + ln) * K + qd * 8;
    const u16* b1p = b0p + 16 * K;
    for (int kc = 0; kc < K; kc += 32) {
        short8 a0 = *(const short8*)(a0p + kc);
        short8 a1 = *(const short8*)(a1p + kc);
        short8 b0 = *(const short8*)(b0p + kc);
        short8 b1 = *(const short8*)(b1p + kc);
        acc[0][0] = MFMA16(a0, b0, acc[0][0]);
        acc[0][1] = MFMA16(a0, b1, acc[0][1]);
        acc[1][0] = MFMA16(a1, b0, acc[1][0]);
        acc[1][1] = MFMA16(a1, b1, acc[1][1]);
    }
#pragma unroll
    for (int i = 0; i < 2; i++)
#pragma unroll
        for (int j = 0; j < 2; j++)
#pragma unroll
            for (int r = 0; r < 4; r++) {
                int m = m_base + i * 16 + qd * 4 + r;
                int n = n_base + j * 16 + ln;
                float v = acc[i][j][r];
                if (MODE == 0) {
                    v += bias[n];
                    int b = m >> 10, s = m & 1023, h = n >> 6, d = n & 63;
                    ((u16*)Cout)[(((long)(b * 8 + h) << 10) + s) * 64 + d] = f2bf(v);
                } else if (MODE == 1) {
                    v += bias[m];
                    int b = n >> 10, t = n & 1023, h = m >> 6, d = m & 63;
                    ((u16*)Cout)[(((long)(b * 8 + h) * 64 + d) << 10) + t] = f2bf(v);
                } else {
                    v += bias[n];
                    // final output: write-once, never re-read on device
                    __builtin_nontemporal_store(v, (float*)Cout + (long)m * N + n);
                }
            }
}

// One block per (b, h, 16-row s-tile). 256 threads = 4 waves.
// cont/pos are NT-scatter-stored DIRECTLY from the MFMA accumulators inside
// phases 1/2 (pos_score IS the phase-2 acc), so there are only 3 barriers and
// no LDS round-trip passes. Stores issue spread across each phase's MFMA loop
// and retire before the phase-ending vmcnt drain. XCD-affinity block remap
// keeps each XCD's K/rel/V read set (~1.6 MB) resident in its private L2.
__global__ __launch_bounds__(256) void score_kernel(const u16* __restrict__ qws,
                                                    const u16* __restrict__ kws,
                                                    const u16* __restrict__ vtws,
                                                    const u16* __restrict__ relws,
                                                    float* __restrict__ out_attn,
                                                    float* __restrict__ out_cont,
                                                    float* __restrict__ out_pos,
                                                    u16* __restrict__ ctx) {
    __shared__ float sc[16 * 1024]; // 64 KB, XOR-swizzled via swz()
    // XCD remap: l%8 = xcd (HW round-robin), 4 bh per xcd, 64 s-tiles per bh
    int l = blockIdx.x;
    int xcd = l & 7, i0 = l >> 3;
    int bh = (xcd << 2) + (i0 >> 6);
    int st = i0 & 63;
    int b = bh >> 3, h = bh & 7;
    int s0 = st * 16;
    int tid = threadIdx.x;
    int w = tid >> 6, lane = tid & 63, qd = lane >> 4, ln = lane & 15;

    const u16* qbase  = qws + ((long)bh << 10) * 64;   // [1024][64]
    const u16* kbase  = kws + ((long)bh << 10) * 64;   // [1024][64]
    const u16* vtbase = vtws + ((long)bh << 6) * 1024; // [64][1024]
    float* attn_base = out_attn + ((long)bh << 20) + (long)s0 * 1024;
    float* cont_base = out_cont + ((long)bh << 20) + (long)s0 * 1024;
    float* pos_base  = out_pos  + ((long)bh << 20) + (long)s0 * 1024;

    // q fragments for the 16-row s-subtile (K=64 -> two 32-chunks)
    short8 qa0 = *(const short8*)(qbase + (s0 + ln) * 64 + qd * 8);
    short8 qa1 = *(const short8*)(qbase + (s0 + ln) * 64 + 32 + qd * 8);

    // ---- Phase 1: content -> sc + direct NT store. Wave w: t in [w*256,..) ----
    for (int tt = 0; tt < 16; tt++) {
        int t0 = w * 256 + tt * 16;
        short8 kb0 = *(const short8*)(kbase + (t0 + ln) * 64 + qd * 8);
        short8 kb1 = *(const short8*)(kbase + (t0 + ln) * 64 + 32 + qd * 8);
        f32x4 acc = {};
        acc = MFMA16(qa0, kb0, acc);
        acc = MFMA16(qa1, kb1, acc);
#pragma unroll
        for (int r = 0; r < 4; r++) {
            int sl = qd * 4 + r;
            int t = t0 + ln;
            __builtin_nontemporal_store(acc[r], &cont_base[sl * 1024 + t]);
            sc[swz(sl, t)] = acc[r];
        }
    }
    __syncthreads();

    // ---- Phase 2: pos accumulate + direct NT store. 65 r-subtiles ----
    int rbase = 1008 - s0;
    for (int rt = w; rt < 65; rt += 4) {
        int r0 = rbase + rt * 16;
        short8 rb0 = *(const short8*)(relws + (r0 + ln) * 64 + qd * 8);
        short8 rb1 = *(const short8*)(relws + (r0 + ln) * 64 + 32 + qd * 8);
        f32x4 acc = {};
        acc = MFMA16(qa0, rb0, acc);
        acc = MFMA16(qa1, rb1, acc);
#pragma unroll
        for (int r = 0; r < 4; r++) {
            int sl = qd * 4 + r;
            int t = rt * 16 + ln + sl - 15; // = r - 1023 + s  (s0 cancels)
            if (t >= 0 && t < 1024) {
                __builtin_nontemporal_store(acc[r], &pos_base[sl * 1024 + t]);
                sc[swz(sl, t)] += acc[r];
            }
        }
    }
    __syncthreads();

    // ---- Phase 3: softmax (scale applied on read). 16 threads/row,
    //      in-place per-thread columns -> no internal barrier needed ----
    {
        int row = tid >> 4;
        int g = tid & 15;
        float ev[64];
        float mx = -1e30f;
#pragma unroll
        for (int i = 0; i < 64; i++) {
            float v = sc[swz(row, g + 16 * i)] * SCALE;
            ev[i] = v;
            mx = fmaxf(mx, v);
        }
        for (int off = 1; off < 16; off <<= 1) mx = fmaxf(mx, __shfl_xor(mx, off, 64));
        float sum = 0.f;
#pragma unroll
        for (int i = 0; i < 64; i++) {
            float e = __expf(ev[i] - mx);
            ev[i] = e;
            sum += e;
        }
        for (int off = 1; off < 16; off <<= 1) sum += __shfl_xor(sum, off, 64);
        float inv = 1.0f / sum;
#pragma unroll
        for (int i = 0; i < 64; i++) sc[swz(row, g + 16 * i)] = ev[i] * inv;
    }
    __syncthreads();

    // ---- Dump attn (coalesced, NT). Phase 4 only reads sc -> no barrier ----
#pragma unroll
    for (int i = 0; i < 16; i++) {
        f32x4 v = *(const f32x4*)&sc[swz(i, tid * 4)];
        __builtin_nontemporal_store(v, (f32x4*)&attn_base[i * 1024 + tid * 4]);
    }

    // ---- Phase 4: o = attn @ v. Wave w -> d-subtile [w*16, w*16+16) ----
    {
        const u16* vrow = vtbase + (w * 16 + ln) * 1024 + qd * 8;
        f32x4 oacc = {};
        for (int kt = 0; kt < 32; kt++) {
            f32x4 x = *(const f32x4*)&sc[swz(ln, kt * 32 + qd * 8)];
            f32x4 y = *(const f32x4*)&sc[swz(ln, kt * 32 + qd * 8 + 4)];
            short8 a = pack8(x, y);
            short8 bf = *(const short8*)(vrow + kt * 32);
            oacc = MFMA16(a, bf, oacc);
        }
#pragma unroll
        for (int r = 0; r < 4; r++) {
            int sl = qd * 4 + r;
            int d = w * 16 + ln;
            ctx[((long)(b * 1024 + s0 + sl)) * 512 + h * 64 + d] = f2bf(oacc[r]);
        }
    }
}

extern "C" void kernel_launch(void* const* d_in, const int* in_sizes, int n_in,
                              void* d_out, int out_size, void* d_ws, size_t ws_size,
                              hipStream_t stream) {
    (void)in_sizes; (void)n_in; (void)out_size; (void)ws_size;
    const float* query   = (const float*)d_in[0];
    const float* key     = (const float*)d_in[1];
    const float* value   = (const float*)d_in[2];
    const float* pos_emb = (const float*)d_in[3];
    const float* Wq = (const float*)d_in[4];
    const float* bq = (const float*)d_in[5];
    const float* Wk = (const float*)d_in[6];
    const float* bk = (const float*)d_in[7];
    const float* Wv = (const float*)d_in[8];
    const float* bv = (const float*)d_in[9];
    const float* Wo = (const float*)d_in[10];
    const float* bo = (const float*)d_in[11];
    const float* Wp = (const float*)d_in[12];
    const float* bp = (const float*)d_in[13];

    // workspace layout (bf16 u16 elements)
    u16* qin  = (u16*)d_ws;            // 4096*512
    u16* kin  = qin + 4096 * 512;
    u16* vin  = kin + 4096 * 512;
    u16* wqb  = vin + 4096 * 512;      // 512*512 each
    u16* wkb  = wqb + 512 * 512;
    u16* wvb  = wkb + 512 * 512;
    u16* wob  = wvb + 512 * 512;
    u16* relb = wob + 512 * 512;       // 2048*64 (row 2047 read-garbage, discarded)
    u16* qws  = relb + 2048 * 64;      // [B,H,S,64]
    u16* kws  = qws + 4 * 8 * 1024 * 64;
    u16* vtws = kws + 4 * 8 * 1024 * 64; // [B,H,64,S]
    u16* ctx  = qin; // alias: qin dead after q-projection

    float* out  = (float*)d_out;
    float* attn = out + 2097152;
    float* cont = attn + 33554432;
    float* pos  = cont + 33554432;

    CvtArgs ca;
    ca.s[0] = query; ca.d[0] = qin;
    ca.s[1] = key;   ca.d[1] = kin;
    ca.s[2] = value; ca.d[2] = vin;
    ca.s[3] = Wq;    ca.d[3] = wqb;
    ca.s[4] = Wk;    ca.d[4] = wkb;
    ca.s[5] = Wv;    ca.d[5] = wvb;
    ca.s[6] = Wo;    ca.d[6] = wob;
    cvt_all<<<dim3(2048, 7), 256, 0, stream>>>(ca);
    rel_kernel<<<512, 256, 0, stream>>>(pos_emb, Wp, bp, relb);

    gemm_kernel<0><<<dim3(64, 8), 256, 0, stream>>>(qin, wqb, bq, qws, 4096, 512, 512);
    gemm_kernel<0><<<dim3(64, 8), 256, 0, stream>>>(kin, wkb, bk, kws, 4096, 512, 512);
    gemm_kernel<1><<<dim3(8, 64), 256, 0, stream>>>(wvb, vin, bv, vtws, 512, 4096, 512);

    score_kernel<<<2048, 256, 0, stream>>>(qws, kws, vtws, relb, attn, cont, pos, ctx);

    gemm_kernel<2><<<dim3(64, 8), 256, 0, stream>>>(ctx, wob, bo, out, 4096, 512, 512);
}

// Round 5
// 602.397 us; speedup vs baseline: 1.0401x; 1.0401x over previous
//
#include <hip/hip_runtime.h>

typedef __attribute__((ext_vector_type(8))) short short8;
typedef __attribute__((ext_vector_type(4))) float f32x4;
typedef unsigned short u16;
typedef unsigned int u32;
typedef unsigned long long u64;

#define MFMA16(a, b, c) __builtin_amdgcn_mfma_f32_16x16x32_bf16((a), (b), (c), 0, 0, 0)
#define SCALE 0.044194173824159216f /* 1/sqrt(512) */

__device__ __forceinline__ u16 f2bf(float f) {
    u32 u = __float_as_uint(f);
    u = (u + 0x7fffu + ((u >> 16) & 1u)) >> 16; // RNE
    return (u16)u;
}

// v_cvt_pk_bf16_f32: D[15:0]=bf16(a), D[31:16]=bf16(b)
__device__ __forceinline__ u32 cvtpk(float a, float b) {
    u32 d;
    asm("v_cvt_pk_bf16_f32 %0, %1, %2" : "=v"(d) : "v"(a), "v"(b));
    return d;
}

// XOR-swizzled index into a [16][512] f32 LDS tile (kernel A)
__device__ __forceinline__ int swzA(int r, int c) {
    return (r << 9) + (c ^ ((r & 7) << 2));
}

struct CvtArgs {
    const float* s[7];
    u16* d[7];
};

// One launch converts q,k,v (y=0..2, 524288 float4) + Wq,Wk,Wv,Wo (y=3..6, 65536)
__global__ __launch_bounds__(256) void cvt_all(CvtArgs a) {
    int which = blockIdx.y;
    int n4 = (which < 3) ? 524288 : 65536;
    int i = blockIdx.x * 256 + threadIdx.x;
    if (i >= n4) return;
    f32x4 v = __builtin_nontemporal_load((const f32x4*)a.s[which] + i);
    u64 p = (u64)f2bf(v[0])
          | ((u64)f2bf(v[1]) << 16)
          | ((u64)f2bf(v[2]) << 32)
          | ((u64)f2bf(v[3]) << 48);
    ((u64*)a.d[which])[i] = p;
}

// rel[r,c] = sum_k pos_emb[r,k] * Wp[c,k] + bp[c], r<2047, c<64 -> bf16
__global__ __launch_bounds__(256) void rel_kernel(const float* __restrict__ pos_emb,
                                                  const float* __restrict__ Wp,
                                                  const float* __restrict__ bp,
                                                  u16* __restrict__ rel) {
    int idx = blockIdx.x * 256 + threadIdx.x;
    if (idx >= 2047 * 64) return;
    int r = idx >> 6, c = idx & 63;
    const float* pe = pos_emb + r * 64;
    const float* w  = Wp + c * 64;
    float acc = bp[c];
#pragma unroll
    for (int k = 0; k < 64; k++) acc += pe[k] * w[k];
    rel[r * 64 + c] = f2bf(acc);
}

// C[M,N] = A[M,K] @ B[N,K]^T, bf16 inputs, 64x64 block tile, 4 waves 2x2.
template <int MODE>
__global__ __launch_bounds__(256) void gemm_kernel(const u16* __restrict__ A,
                                                   const u16* __restrict__ B,
                                                   const float* __restrict__ bias,
                                                   void* __restrict__ Cout,
                                                   int M, int N, int K) {
    int tid = threadIdx.x;
    int w = tid >> 6, lane = tid & 63;
    int wi = w >> 1, wj = w & 1;
    int qd = lane >> 4, ln = lane & 15;
    int m_base = blockIdx.x * 64 + wi * 32;
    int n_base = blockIdx.y * 64 + wj * 32;
    f32x4 acc[2][2] = {};
    const u16* a0p = A + (long)(m_base + ln) * K + qd * 8;
    const u16* a1p = a0p + 16 * K;
    const u16* b0p = B + (long)(n_base + ln) * K + qd * 8;
    const u16* b1p = b0p + 16 * K;
    for (int kc = 0; kc < K; kc += 32) {
        short8 a0 = *(const short8*)(a0p + kc);
        short8 a1 = *(const short8*)(a1p + kc);
        short8 b0 = *(const short8*)(b0p + kc);
        short8 b1 = *(const short8*)(b1p + kc);
        acc[0][0] = MFMA16(a0, b0, acc[0][0]);
        acc[0][1] = MFMA16(a0, b1, acc[0][1]);
        acc[1][0] = MFMA16(a1, b0, acc[1][0]);
        acc[1][1] = MFMA16(a1, b1, acc[1][1]);
    }
#pragma unroll
    for (int i = 0; i < 2; i++)
#pragma unroll
        for (int j = 0; j < 2; j++)
#pragma unroll
            for (int r = 0; r < 4; r++) {
                int m = m_base + i * 16 + qd * 4 + r;
                int n = n_base + j * 16 + ln;
                float v = acc[i][j][r];
                if (MODE == 0) {
                    v += bias[n];
                    int b = m >> 10, s = m & 1023, h = n >> 6, d = n & 63;
                    ((u16*)Cout)[(((long)(b * 8 + h) << 10) + s) * 64 + d] = f2bf(v);
                } else if (MODE == 1) {
                    v += bias[m];
                    int b = n >> 10, t = n & 1023, h = m >> 6, d = m & 63;
                    ((u16*)Cout)[(((long)(b * 8 + h) * 64 + d) << 10) + t] = f2bf(v);
                } else {
                    v += bias[n];
                    __builtin_nontemporal_store(v, (float*)Cout + (long)m * N + n);
                }
            }
}

// ---- Kernel A: cont + pos scores -> HBM (coalesced NT). ----
// 32 KB LDS [16][512], two t-halves. VGPR-lean, no softmax/PV state
// -> ~5 blocks/CU vs the fused kernel's 2. XCD remap keeps K/rel in XCD-L2.
__global__ __launch_bounds__(256) void score_cp(const u16* __restrict__ qws,
                                                const u16* __restrict__ kws,
                                                const u16* __restrict__ relws,
                                                float* __restrict__ out_cont,
                                                float* __restrict__ out_pos) {
    __shared__ float sc[16 * 512]; // 32 KB
    int l = blockIdx.x;
    int xcd = l & 7, i0 = l >> 3;
    int bh = (xcd << 2) + (i0 >> 6);
    int st = i0 & 63;
    int s0 = st * 16;
    int tid = threadIdx.x;
    int w = tid >> 6, lane = tid & 63, qd = lane >> 4, ln = lane & 15;

    const u16* qbase = qws + ((long)bh << 10) * 64;
    const u16* kbase = kws + ((long)bh << 10) * 64;
    float* cont_base = out_cont + ((long)bh << 20) + (long)s0 * 1024;
    float* pos_base  = out_pos  + ((long)bh << 20) + (long)s0 * 1024;

    short8 qa0 = *(const short8*)(qbase + (s0 + ln) * 64 + qd * 8);
    short8 qa1 = *(const short8*)(qbase + (s0 + ln) * 64 + 32 + qd * 8);

    int rbase = 1008 - s0;
#pragma unroll
    for (int half = 0; half < 2; half++) {
        int tbase = half * 512;
        // -- content scores for t in [tbase, tbase+512) --
        for (int tt = 0; tt < 8; tt++) {
            int t0 = tbase + w * 128 + tt * 16;
            short8 kb0 = *(const short8*)(kbase + (t0 + ln) * 64 + qd * 8);
            short8 kb1 = *(const short8*)(kbase + (t0 + ln) * 64 + 32 + qd * 8);
            f32x4 acc = {};
            acc = MFMA16(qa0, kb0, acc);
            acc = MFMA16(qa1, kb1, acc);
#pragma unroll
            for (int r = 0; r < 4; r++)
                sc[swzA(qd * 4 + r, t0 + ln - tbase)] = acc[r];
        }
        __syncthreads();
#pragma unroll
        for (int i = 0; i < 8; i++) {
            int idx = i * 256 + tid;
            int row = idx >> 7, c4 = (idx & 127) * 4;
            f32x4 v = *(const f32x4*)&sc[swzA(row, c4)];
            __builtin_nontemporal_store(v, (f32x4*)&cont_base[row * 1024 + tbase + c4]);
        }
        __syncthreads();
        // -- pos scores: every (sl,t) in this half written exactly once.
        //    t = rt*16+ln+sl-15 => half0 needs rt<=32, half1 needs rt>=32. --
        int rtlo = half ? 32 : 0, rthi = half ? 64 : 32;
        for (int rt = rtlo + w; rt <= rthi; rt += 4) {
            int r0 = rbase + rt * 16;
            short8 rb0 = *(const short8*)(relws + (r0 + ln) * 64 + qd * 8);
            short8 rb1 = *(const short8*)(relws + (r0 + ln) * 64 + 32 + qd * 8);
            f32x4 acc = {};
            acc = MFMA16(qa0, rb0, acc);
            acc = MFMA16(qa1, rb1, acc);
#pragma unroll
            for (int r = 0; r < 4; r++) {
                int sl = qd * 4 + r;
                int t = rt * 16 + ln + sl - 15;
                if (t >= tbase && t < tbase + 512)
                    sc[swzA(sl, t - tbase)] = acc[r];
            }
        }
        __syncthreads();
#pragma unroll
        for (int i = 0; i < 8; i++) {
            int idx = i * 256 + tid;
            int row = idx >> 7, c4 = (idx & 127) * 4;
            f32x4 v = *(const f32x4*)&sc[swzA(row, c4)];
            __builtin_nontemporal_store(v, (f32x4*)&pos_base[row * 1024 + tbase + c4]);
        }
        __syncthreads();
    }
}

// ---- Kernel B: score = (cont+pos)*SCALE -> softmax (all-register) -> attn,
// pack P to swizzled bf16 LDS (32 KB) -> PV MFMA -> ctx. ----
__global__ __launch_bounds__(256) void softmax_pv(const float* __restrict__ in_cont,
                                                  const float* __restrict__ in_pos,
                                                  const u16* __restrict__ vtws,
                                                  float* __restrict__ out_attn,
                                                  u16* __restrict__ ctx) {
    __shared__ u16 pl[16 * 1024]; // 32 KB bf16, 16B-granule XOR swizzle by row
    int l = blockIdx.x;
    int xcd = l & 7, i0 = l >> 3;
    int bh = (xcd << 2) + (i0 >> 6);
    int st = i0 & 63;
    int b = bh >> 3, h = bh & 7;
    int s0 = st * 16;
    int tid = threadIdx.x;
    int w = tid >> 6, lane = tid & 63, qd = lane >> 4, ln = lane & 15;
    int row = tid >> 4, g = tid & 15;

    const u16* vtbase = vtws + ((long)bh << 6) * 1024;
    const f32x4* cv = (const f32x4*)(in_cont + ((long)bh << 20) + (long)(s0 + row) * 1024);
    const f32x4* pv = (const f32x4*)(in_pos  + ((long)bh << 20) + (long)(s0 + row) * 1024);
    f32x4* av = (f32x4*)(out_attn + ((long)bh << 20) + (long)(s0 + row) * 1024);

    // thread owns row `row`, cols 4g+64i+j (j<4, i<16): 256B segments/row, coalesced
    float ev[64];
    float mx = -1e30f;
#pragma unroll
    for (int i = 0; i < 16; i++) {
        f32x4 c = __builtin_nontemporal_load(cv + g + 16 * i);
        f32x4 p = __builtin_nontemporal_load(pv + g + 16 * i);
#pragma unroll
        for (int j = 0; j < 4; j++) {
            float v = (c[j] + p[j]) * SCALE;
            ev[i * 4 + j] = v;
            mx = fmaxf(mx, v);
        }
    }
    for (int off = 1; off < 16; off <<= 1) mx = fmaxf(mx, __shfl_xor(mx, off, 64));
    float sum = 0.f;
#pragma unroll
    for (int i = 0; i < 64; i++) {
        float e = __expf(ev[i] - mx);
        ev[i] = e;
        sum += e;
    }
    for (int off = 1; off < 16; off <<= 1) sum += __shfl_xor(sum, off, 64);
    float inv = 1.0f / sum;
#pragma unroll
    for (int i = 0; i < 16; i++) {
        f32x4 a;
#pragma unroll
        for (int j = 0; j < 4; j++) a[j] = ev[i * 4 + j] * inv;
        __builtin_nontemporal_store(a, av + g + 16 * i);
        // pack 4 attn vals -> bf16x4 -> swizzled LDS (8B write)
        u32 lo = cvtpk(a[0], a[1]);
        u32 hi = cvtpk(a[2], a[3]);
        int g16 = (g >> 1) + 8 * i;              // 16B granule index (0..127)
        int addr = row * 2048 + ((g16 ^ (row & 7)) << 4) + (g & 1) * 8;
        *(u64*)((char*)pl + addr) = ((u64)hi << 32) | lo;
    }
    __syncthreads();

    // PV: wave w -> d-subtile [w*16, w*16+16). P frag = pl[ln][kt*32+qd*8..+8]
    {
        const u16* vrow = vtbase + (w * 16 + ln) * 1024 + qd * 8;
        f32x4 oacc = {};
        for (int kt = 0; kt < 32; kt++) {
            int g16 = kt * 4 + qd;
            int addr = ln * 2048 + ((g16 ^ (ln & 7)) << 4);
            short8 a = *(const short8*)((const char*)pl + addr);
            short8 bf = *(const short8*)(vrow + kt * 32);
            oacc = MFMA16(a, bf, oacc);
        }
#pragma unroll
        for (int r = 0; r < 4; r++) {
            int sl = qd * 4 + r;
            int d = w * 16 + ln;
            ctx[((long)(b * 1024 + s0 + sl)) * 512 + h * 64 + d] = f2bf(oacc[r]);
        }
    }
}

extern "C" void kernel_launch(void* const* d_in, const int* in_sizes, int n_in,
                              void* d_out, int out_size, void* d_ws, size_t ws_size,
                              hipStream_t stream) {
    (void)in_sizes; (void)n_in; (void)out_size; (void)ws_size;
    const float* query   = (const float*)d_in[0];
    const float* key     = (const float*)d_in[1];
    const float* value   = (const float*)d_in[2];
    const float* pos_emb = (const float*)d_in[3];
    const float* Wq = (const float*)d_in[4];
    const float* bq = (const float*)d_in[5];
    const float* Wk = (const float*)d_in[6];
    const float* bk = (const float*)d_in[7];
    const float* Wv = (const float*)d_in[8];
    const float* bv = (const float*)d_in[9];
    const float* Wo = (const float*)d_in[10];
    const float* bo = (const float*)d_in[11];
    const float* Wp = (const float*)d_in[12];
    const float* bp = (const float*)d_in[13];

    // workspace layout (bf16 u16 elements)
    u16* qin  = (u16*)d_ws;            // 4096*512
    u16* kin  = qin + 4096 * 512;
    u16* vin  = kin + 4096 * 512;
    u16* wqb  = vin + 4096 * 512;      // 512*512 each
    u16* wkb  = wqb + 512 * 512;
    u16* wvb  = wkb + 512 * 512;
    u16* wob  = wvb + 512 * 512;
    u16* relb = wob + 512 * 512;       // 2048*64 (row 2047 read-garbage, discarded)
    u16* qws  = relb + 2048 * 64;      // [B,H,S,64]
    u16* kws  = qws + 4 * 8 * 1024 * 64;
    u16* vtws = kws + 4 * 8 * 1024 * 64; // [B,H,64,S]
    u16* ctx  = qin; // alias: qin dead after q-projection

    float* out  = (float*)d_out;
    float* attn = out + 2097152;
    float* cont = attn + 33554432;
    float* pos  = cont + 33554432;

    CvtArgs ca;
    ca.s[0] = query; ca.d[0] = qin;
    ca.s[1] = key;   ca.d[1] = kin;
    ca.s[2] = value; ca.d[2] = vin;
    ca.s[3] = Wq;    ca.d[3] = wqb;
    ca.s[4] = Wk;    ca.d[4] = wkb;
    ca.s[5] = Wv;    ca.d[5] = wvb;
    ca.s[6] = Wo;    ca.d[6] = wob;
    cvt_all<<<dim3(2048, 7), 256, 0, stream>>>(ca);
    rel_kernel<<<512, 256, 0, stream>>>(pos_emb, Wp, bp, relb);

    gemm_kernel<0><<<dim3(64, 8), 256, 0, stream>>>(qin, wqb, bq, qws, 4096, 512, 512);
    gemm_kernel<0><<<dim3(64, 8), 256, 0, stream>>>(kin, wkb, bk, kws, 4096, 512, 512);
    gemm_kernel<1><<<dim3(8, 64), 256, 0, stream>>>(wvb, vin, bv, vtws, 512, 4096, 512);

    score_cp<<<2048, 256, 0, stream>>>(qws, kws, relb, cont, pos);
    softmax_pv<<<2048, 256, 0, stream>>>(cont, pos, vtws, attn, ctx);

    gemm_kernel<2><<<dim3(64, 8), 256, 0, stream>>>(ctx, wob, bo, out, 4096, 512, 512);
}

// Round 6
// 561.070 us; speedup vs baseline: 1.1167x; 1.0737x over previous
//
#include <hip/hip_runtime.h>

typedef __attribute__((ext_vector_type(8))) short short8;
typedef __attribute__((ext_vector_type(4))) float f32x4;
typedef unsigned short u16;
typedef unsigned int u32;
typedef unsigned long long u64;

#define MFMA16(a, b, c) __builtin_amdgcn_mfma_f32_16x16x32_bf16((a), (b), (c), 0, 0, 0)
#define SCALE 0.044194173824159216f /* 1/sqrt(512) */

__device__ __forceinline__ u16 f2bf(float f) {
    u32 u = __float_as_uint(f);
    u = (u + 0x7fffu + ((u >> 16) & 1u)) >> 16; // RNE
    return (u16)u;
}

// pack 8 f32 -> 8 bf16 (RNE) via v_cvt_pk_bf16_f32 (no builtin on gfx950)
__device__ __forceinline__ short8 pack8(f32x4 x, f32x4 y) {
    union { u32 w[4]; short8 s; } u;
    asm("v_cvt_pk_bf16_f32 %0, %1, %2" : "=v"(u.w[0]) : "v"(x[0]), "v"(x[1]));
    asm("v_cvt_pk_bf16_f32 %0, %1, %2" : "=v"(u.w[1]) : "v"(x[2]), "v"(x[3]));
    asm("v_cvt_pk_bf16_f32 %0, %1, %2" : "=v"(u.w[2]) : "v"(y[0]), "v"(y[1]));
    asm("v_cvt_pk_bf16_f32 %0, %1, %2" : "=v"(u.w[3]) : "v"(y[2]), "v"(y[3]));
    return u.s;
}

// LDS-only barrier: wait LDS ops, then raw s_barrier. Deliberately does NOT
// drain vmcnt, so non-temporal store bursts stay in flight across phases
// (in-kernel, no global store is ever re-read -> correct).
__device__ __forceinline__ void ldsbar() {
    asm volatile("s_waitcnt lgkmcnt(0)" ::: "memory");
    __builtin_amdgcn_s_barrier();
}

// XOR-swizzled LDS index for a [16][1024] f32 tile: spreads rows across bank
// groups so column-wise ds_read_b128 (phase 4) stays at the 2-lane/bank floor.
__device__ __forceinline__ int swz(int r, int c) {
    return (r << 10) + (c ^ ((r & 7) << 2));
}

struct CvtArgs {
    const float* s[7];
    u16* d[7];
};

// One launch converts q,k,v (y=0..2, 524288 float4) + Wq,Wk,Wv,Wo (y=3..6, 65536)
__global__ __launch_bounds__(256) void cvt_all(CvtArgs a) {
    int which = blockIdx.y;
    int n4 = (which < 3) ? 524288 : 65536;
    int i = blockIdx.x * 256 + threadIdx.x;
    if (i >= n4) return;
    f32x4 v = __builtin_nontemporal_load((const f32x4*)a.s[which] + i);
    u64 p = (u64)f2bf(v[0])
          | ((u64)f2bf(v[1]) << 16)
          | ((u64)f2bf(v[2]) << 32)
          | ((u64)f2bf(v[3]) << 48);
    ((u64*)a.d[which])[i] = p;
}

// rel[r,c] = sum_k pos_emb[r,k] * Wp[c,k] + bp[c], r<2047, c<64 -> bf16
__global__ __launch_bounds__(256) void rel_kernel(const float* __restrict__ pos_emb,
                                                  const float* __restrict__ Wp,
                                                  const float* __restrict__ bp,
                                                  u16* __restrict__ rel) {
    int idx = blockIdx.x * 256 + threadIdx.x;
    if (idx >= 2047 * 64) return;
    int r = idx >> 6, c = idx & 63;
    const float* pe = pos_emb + r * 64;
    const float* w  = Wp + c * 64;
    float acc = bp[c];
#pragma unroll
    for (int k = 0; k < 64; k++) acc += pe[k] * w[k];
    rel[r * 64 + c] = f2bf(acc);
}

// C[M,N] = A[M,K] @ B[N,K]^T, bf16 inputs, 64x64 block tile, 4 waves 2x2.
template <int MODE>
__global__ __launch_bounds__(256) void gemm_kernel(const u16* __restrict__ A,
                                                   const u16* __restrict__ B,
                                                   const float* __restrict__ bias,
                                                   void* __restrict__ Cout,
                                                   int M, int N, int K) {
    int tid = threadIdx.x;
    int w = tid >> 6, lane = tid & 63;
    int wi = w >> 1, wj = w & 1;
    int qd = lane >> 4, ln = lane & 15;
    int m_base = blockIdx.x * 64 + wi * 32;
    int n_base = blockIdx.y * 64 + wj * 32;
    f32x4 acc[2][2] = {};
    const u16* a0p = A + (long)(m_base + ln) * K + qd * 8;
    const u16* a1p = a0p + 16 * K;
    const u16* b0p = B + (long)(n_base + ln) * K + qd * 8;
    const u16* b1p = b0p + 16 * K;
    for (int kc = 0; kc < K; kc += 32) {
        short8 a0 = *(const short8*)(a0p + kc);
        short8 a1 = *(const short8*)(a1p + kc);
        short8 b0 = *(const short8*)(b0p + kc);
        short8 b1 = *(const short8*)(b1p + kc);
        acc[0][0] = MFMA16(a0, b0, acc[0][0]);
        acc[0][1] = MFMA16(a0, b1, acc[0][1]);
        acc[1][0] = MFMA16(a1, b0, acc[1][0]);
        acc[1][1] = MFMA16(a1, b1, acc[1][1]);
    }
#pragma unroll
    for (int i = 0; i < 2; i++)
#pragma unroll
        for (int j = 0; j < 2; j++)
#pragma unroll
            for (int r = 0; r < 4; r++) {
                int m = m_base + i * 16 + qd * 4 + r;
                int n = n_base + j * 16 + ln;
                float v = acc[i][j][r];
                if (MODE == 0) {
                    v += bias[n];
                    int b = m >> 10, s = m & 1023, h = n >> 6, d = n & 63;
                    ((u16*)Cout)[(((long)(b * 8 + h) << 10) + s) * 64 + d] = f2bf(v);
                } else if (MODE == 1) {
                    v += bias[m];
                    int b = n >> 10, t = n & 1023, h = m >> 6, d = m & 63;
                    ((u16*)Cout)[(((long)(b * 8 + h) * 64 + d) << 10) + t] = f2bf(v);
                } else {
                    v += bias[n];
                    __builtin_nontemporal_store(v, (float*)Cout + (long)m * N + n);
                }
            }
}

// One block per (b, h, 16-row s-tile). 256 threads = 4 waves. R3 structure with
// store/wait choreography: all barriers are LDS-only (no vmcnt drain); each NT
// store burst is issued AFTER the global loads that follow it in program order
// (in-order vmcnt!), so subsequent load-waits don't force a store drain:
//   cont stores -> end of phase 2 (drain under softmax's load-free window)
//   pos  stores -> during phase 3a
//   attn stores -> after phase 4's MFMA loop (drain at kernel end, overlapping
//                  the next block's phase 1)
__global__ __launch_bounds__(256) void score_kernel(const u16* __restrict__ qws,
                                                    const u16* __restrict__ kws,
                                                    const u16* __restrict__ vtws,
                                                    const u16* __restrict__ relws,
                                                    float* __restrict__ out_attn,
                                                    float* __restrict__ out_cont,
                                                    float* __restrict__ out_pos,
                                                    u16* __restrict__ ctx) {
    __shared__ float sc[16 * 1024]; // 64 KB, XOR-swizzled via swz()
    // XCD remap: l%8 = xcd (HW round-robin), 4 bh per xcd, 64 s-tiles per bh
    int l = blockIdx.x;
    int xcd = l & 7, i0 = l >> 3;
    int bh = (xcd << 2) + (i0 >> 6);
    int st = i0 & 63;
    int b = bh >> 3, h = bh & 7;
    int s0 = st * 16;
    int tid = threadIdx.x;
    int w = tid >> 6, lane = tid & 63, qd = lane >> 4, ln = lane & 15;
    int row = tid >> 4, g = tid & 15;

    const u16* qbase  = qws + ((long)bh << 10) * 64;   // [1024][64]
    const u16* kbase  = kws + ((long)bh << 10) * 64;   // [1024][64]
    const u16* vtbase = vtws + ((long)bh << 6) * 1024; // [64][1024]
    float* attn_base = out_attn + ((long)bh << 20) + (long)s0 * 1024;
    float* cont_base = out_cont + ((long)bh << 20) + (long)s0 * 1024;
    float* pos_base  = out_pos  + ((long)bh << 20) + (long)s0 * 1024;

    // q fragments for the 16-row s-subtile (K=64 -> two 32-chunks)
    short8 qa0 = *(const short8*)(qbase + (s0 + ln) * 64 + qd * 8);
    short8 qa1 = *(const short8*)(qbase + (s0 + ln) * 64 + 32 + qd * 8);

    // ---- Phase 1: content -> sc. Wave w covers t in [w*256, w*256+256) ----
    for (int tt = 0; tt < 16; tt++) {
        int t0 = w * 256 + tt * 16;
        short8 kb0 = *(const short8*)(kbase + (t0 + ln) * 64 + qd * 8);
        short8 kb1 = *(const short8*)(kbase + (t0 + ln) * 64 + 32 + qd * 8);
        f32x4 acc = {};
        acc = MFMA16(qa0, kb0, acc);
        acc = MFMA16(qa1, kb1, acc);
#pragma unroll
        for (int r = 0; r < 4; r++) sc[swz(qd * 4 + r, t0 + ln)] = acc[r];
    }
    ldsbar();

    // ---- Cache cont in regs (LDS reads only; stores deferred to phase 2) ----
    f32x4 csave[16];
#pragma unroll
    for (int i = 0; i < 16; i++) csave[i] = *(const f32x4*)&sc[swz(i, tid * 4)];
    ldsbar();

    // ---- Phase 2: pos accumulate into sc. 65 r-subtiles ----
    int rbase = 1008 - s0;
    for (int rt = w; rt < 65; rt += 4) {
        int r0 = rbase + rt * 16;
        short8 rb0 = *(const short8*)(relws + (r0 + ln) * 64 + qd * 8);
        short8 rb1 = *(const short8*)(relws + (r0 + ln) * 64 + 32 + qd * 8);
        f32x4 acc = {};
        acc = MFMA16(qa0, rb0, acc);
        acc = MFMA16(qa1, rb1, acc);
#pragma unroll
        for (int r = 0; r < 4; r++) {
            int sl = qd * 4 + r;
            int t = rt * 16 + ln + sl - 15; // = r - 1023 + s  (s0 cancels)
            if (t >= 0 && t < 1024) sc[swz(sl, t)] += acc[r];
        }
    }
    // cont NT stores from regs — issued after ALL rel loads, so no later
    // load-wait in this phase drains them; they retire under phase 3.
#pragma unroll
    for (int i = 0; i < 16; i++)
        __builtin_nontemporal_store(csave[i], (f32x4*)&cont_base[i * 1024 + tid * 4]);
    ldsbar();

    // ---- Phase 3a: pos dump (= sc - cont) + softmax reads (no LDS writes) ----
#pragma unroll
    for (int i = 0; i < 16; i++) {
        f32x4 v = *(const f32x4*)&sc[swz(i, tid * 4)];
        __builtin_nontemporal_store(v - csave[i], (f32x4*)&pos_base[i * 1024 + tid * 4]);
    }
    float ev[64];
    float inv;
    {
        float mx = -1e30f;
#pragma unroll
        for (int i = 0; i < 64; i++) {
            float v = sc[swz(row, g + 16 * i)] * SCALE;
            ev[i] = v;
            mx = fmaxf(mx, v);
        }
        for (int off = 1; off < 16; off <<= 1) mx = fmaxf(mx, __shfl_xor(mx, off, 64));
        float sum = 0.f;
#pragma unroll
        for (int i = 0; i < 64; i++) {
            float e = __expf(ev[i] - mx);
            ev[i] = e;
            sum += e;
        }
        for (int off = 1; off < 16; off <<= 1) sum += __shfl_xor(sum, off, 64);
        inv = 1.0f / sum;
    }
    ldsbar(); // all reads of pre-softmax sc complete before writeback

    // ---- Phase 3b: writeback attn values into sc ----
#pragma unroll
    for (int i = 0; i < 64; i++) sc[swz(row, g + 16 * i)] = ev[i] * inv;
    ldsbar();

    // ---- Phase 4: o = attn @ v. Wave w -> d-subtile [w*16, w*16+16) ----
    {
        const u16* vrow = vtbase + (w * 16 + ln) * 1024 + qd * 8;
        f32x4 oacc = {};
        for (int kt = 0; kt < 32; kt++) {
            f32x4 x = *(const f32x4*)&sc[swz(ln, kt * 32 + qd * 8)];
            f32x4 y = *(const f32x4*)&sc[swz(ln, kt * 32 + qd * 8 + 4)];
            short8 a = pack8(x, y);
            short8 bf = *(const short8*)(vrow + kt * 32);
            oacc = MFMA16(a, bf, oacc);
        }
#pragma unroll
        for (int r = 0; r < 4; r++) {
            int sl = qd * 4 + r;
            int d = w * 16 + ln;
            ctx[((long)(b * 1024 + s0 + sl)) * 512 + h * 64 + d] = f2bf(oacc[r]);
        }
    }

    // ---- attn dump last: stores stay in flight to kernel end (free drain) ----
#pragma unroll
    for (int i = 0; i < 16; i++) {
        f32x4 v = *(const f32x4*)&sc[swz(i, tid * 4)];
        __builtin_nontemporal_store(v, (f32x4*)&attn_base[i * 1024 + tid * 4]);
    }
}

extern "C" void kernel_launch(void* const* d_in, const int* in_sizes, int n_in,
                              void* d_out, int out_size, void* d_ws, size_t ws_size,
                              hipStream_t stream) {
    (void)in_sizes; (void)n_in; (void)out_size; (void)ws_size;
    const float* query   = (const float*)d_in[0];
    const float* key     = (const float*)d_in[1];
    const float* value   = (const float*)d_in[2];
    const float* pos_emb = (const float*)d_in[3];
    const float* Wq = (const float*)d_in[4];
    const float* bq = (const float*)d_in[5];
    const float* Wk = (const float*)d_in[6];
    const float* bk = (const float*)d_in[7];
    const float* Wv = (const float*)d_in[8];
    const float* bv = (const float*)d_in[9];
    const float* Wo = (const float*)d_in[10];
    const float* bo = (const float*)d_in[11];
    const float* Wp = (const float*)d_in[12];
    const float* bp = (const float*)d_in[13];

    // workspace layout (bf16 u16 elements)
    u16* qin  = (u16*)d_ws;            // 4096*512
    u16* kin  = qin + 4096 * 512;
    u16* vin  = kin + 4096 * 512;
    u16* wqb  = vin + 4096 * 512;      // 512*512 each
    u16* wkb  = wqb + 512 * 512;
    u16* wvb  = wkb + 512 * 512;
    u16* wob  = wvb + 512 * 512;
    u16* relb = wob + 512 * 512;       // 2048*64 (row 2047 read-garbage, discarded)
    u16* qws  = relb + 2048 * 64;      // [B,H,S,64]
    u16* kws  = qws + 4 * 8 * 1024 * 64;
    u16* vtws = kws + 4 * 8 * 1024 * 64; // [B,H,64,S]
    u16* ctx  = qin; // alias: qin dead after q-projection

    float* out  = (float*)d_out;
    float* attn = out + 2097152;
    float* cont = attn + 33554432;
    float* pos  = cont + 33554432;

    CvtArgs ca;
    ca.s[0] = query; ca.d[0] = qin;
    ca.s[1] = key;   ca.d[1] = kin;
    ca.s[2] = value; ca.d[2] = vin;
    ca.s[3] = Wq;    ca.d[3] = wqb;
    ca.s[4] = Wk;    ca.d[4] = wkb;
    ca.s[5] = Wv;    ca.d[5] = wvb;
    ca.s[6] = Wo;    ca.d[6] = wob;
    cvt_all<<<dim3(2048, 7), 256, 0, stream>>>(ca);
    rel_kernel<<<512, 256, 0, stream>>>(pos_emb, Wp, bp, relb);

    gemm_kernel<0><<<dim3(64, 8), 256, 0, stream>>>(qin, wqb, bq, qws, 4096, 512, 512);
    gemm_kernel<0><<<dim3(64, 8), 256, 0, stream>>>(kin, wkb, bk, kws, 4096, 512, 512);
    gemm_kernel<1><<<dim3(8, 64), 256, 0, stream>>>(wvb, vin, bv, vtws, 512, 4096, 512);

    score_kernel<<<2048, 256, 0, stream>>>(qws, kws, vtws, relb, attn, cont, pos, ctx);

    gemm_kernel<2><<<dim3(64, 8), 256, 0, stream>>>(ctx, wob, bo, out, 4096, 512, 512);
}